// Round 8
// baseline (216.573 us; speedup 1.0000x reference)
//
#include <hip/hip_runtime.h>

// ModulatedConv2d: B=16, IN=512, OUT=512, STYLE=512, K=3, H=W=32
// out[b,o] = scale[b,o] * conv2d(x[b,i]*s[b,i], W[o,i])   (shared weights!)
// Conv = one implicit GEMM: M=512 out-ch, N=16384 (b,px), K=9x512.
// x staged as zero-padded NHWC bf16 -> no boundary masking.
//
// R8:  reg-staged A+B LDS pipeline, 1 __syncthreads/step: 96.6us.
// R12: BK=64 scalarized: 91.6us, MfmaUtil 35%.
// R13/R14: B direct-from-global (same-step / step-ahead): 162/160us --
//      scattered 64B-segment B loads are VMEM-throughput-bound. Dead end.
// R15: raw lgkm-only barrier = R12 exactly (91.6us) -> vmcnt drain was NOT
//      the residual. Conclusion: LDS PIPE BOUND. Per CU-step 192 b128 ops
//      x ~12cy = 2300cy vs MFMA 1242cy/SIMD; total frag-read volume at
//      64x64 wave tiles = 2.42GB + 1.21GB writes = ~69us of LDS pipe.
// R16 (this): BIGGER WAVE TILES to cut traffic. Wave 128x64 (reads
//      (128+64)/(128*64): 2.42->1.81GB), block 256x128 (writes ->0.91GB).
//      LDS floor ~52us, MFMA floor 37us. Grid 256 = 1 block/CU, 4 waves,
//      1 wave/SIMD (occupancy counter will read low -- expected). Intra-
//      wave overlap: both k-halves' ds_reads issued async before MFMA k0.
//      LDS dbuf 96KB. VGPR ~300 @ launch_bounds(256,1); spill tripwire =
//      WRITE_SIZE >> 33MB. Keep raw SYNC, reg staging, XOR swizzle.
//      Predict: conv ~58-68us, MfmaUtil 50-58%, total ~150us.

#define BATCH   16
#define CIN     512
#define COUT    512
#define IMG     32
#define PAD_IMG 34

static constexpr float AFF_SCALE = 0.044194173824159216f;  // 1/sqrt(512)
static constexpr float W_SCALE   = 0.014731391274719739f;  // 1/sqrt(512*9)

typedef __bf16 bf16x8 __attribute__((ext_vector_type(8)));
typedef float  f32x4  __attribute__((ext_vector_type(4)));

__device__ inline unsigned short f2bf(float f) {
    union { float f; unsigned int u; } v; v.f = f;
    unsigned int u = v.u;
    unsigned int r = (u + 0x7FFFu + ((u >> 16) & 1u)) >> 16;
    return (unsigned short)r;
}

__device__ inline float waveReduceSum(float v) {
    #pragma unroll
    for (int off = 32; off > 0; off >>= 1) v += __shfl_xor(v, off, 64);
    return v;
}

// ---- kernel 1: fused prep ----
__global__ void prep1(const float* __restrict__ cw,
                      const float* __restrict__ style,
                      const float* __restrict__ aw,
                      const float* __restrict__ ab,
                      unsigned short* __restrict__ w_t,
                      float* __restrict__ wsq,
                      float* __restrict__ s_out) {
    const int tid = threadIdx.x;
    if (blockIdx.x < 1024) {
        __shared__ float wl[2304];
        const float* src = cw + (size_t)blockIdx.x * 2304;
        for (int j = tid; j < 2304; j += 256) wl[j] = src[j];
        __syncthreads();
        const int idx = blockIdx.x * 256 + tid;       // o*512 + i
        const int base = tid * 9;
        float acc = 0.f;
        #pragma unroll
        for (int e = 0; e < 9; ++e) {
            float v = wl[base + e];
            acc += v * v;
            w_t[e * (COUT * CIN) + idx] = f2bf(v);
        }
        wsq[idx] = acc;
    } else {
        const int q = blockIdx.x - 1024;              // 0..2047
        const int b = q >> 7;
        const int i = (q & 127) * 4 + (tid >> 6);
        const int lane = tid & 63;
        float sum = 0.f;
        #pragma unroll
        for (int k = 0; k < 512; k += 64)
            sum += style[b * 512 + k + lane] * aw[i * 512 + k + lane];
        sum = waveReduceSum(sum);
        if (lane == 0)
            s_out[b * 512 + i] = sum * AFF_SCALE + ab[i] + 1.0f;
    }
}

// ---- kernel 2: fused xpad + scale ----
__global__ void prep2(const float* __restrict__ x,
                      const float* __restrict__ s_in,
                      const float* __restrict__ wsq,
                      unsigned short* __restrict__ xpad,
                      float* __restrict__ scl) {
    const int tid = threadIdx.x;
    if (blockIdx.x >= 4352) {
        const int q = blockIdx.x - 4352;              // 0..2047
        const int b = q >> 7;                         // 0..15
        const int o = (q & 127) * 4 + (tid >> 6);     // 0..511
        const int lane = tid & 63;
        float sum = 0.f;
        #pragma unroll
        for (int i = 0; i < 512; i += 64) {
            float sv = s_in[b * 512 + i + lane];
            sum += sv * sv * wsq[o * 512 + i + lane];
        }
        sum = waveReduceSum(sum);
        if (lane == 0)
            scl[b * 512 + o] = W_SCALE * rsqrtf(W_SCALE * W_SCALE * sum + 1e-8f);
        return;
    }
    const int c0   = blockIdx.x & 7;                  // *64 channels
    const int rest = blockIdx.x >> 3;                 // 0..543
    const int hh   = rest % 34;
    const int b    = rest / 34;
    const int c0b  = c0 * 64;
    unsigned short* rowbase = xpad + (((size_t)b * PAD_IMG + hh) * PAD_IMG) * 512;

    if (hh == 0 || hh == PAD_IMG - 1) {
        for (int j = tid; j < 34 * 32; j += 256) {
            int ww = j >> 5, cp = (j & 31) * 2;
            *(unsigned int*)(rowbase + (size_t)ww * 512 + c0b + cp) = 0u;
        }
        return;
    }

    __shared__ float t[64][33];
    const int h = hh - 1;
    {
        const int wx = tid & 31;
        const int cb = (tid >> 5) * 8;
        const float* xb = x + (((size_t)b * 512 + c0b + cb) * IMG + h) * IMG + wx;
        #pragma unroll
        for (int j = 0; j < 8; ++j)
            t[cb + j][wx] = xb[(size_t)j * (IMG * IMG)] * s_in[b * 512 + c0b + cb + j];
    }
    __syncthreads();
    {
        const int p  = tid >> 3;
        const int cc = (tid & 7) * 8;
        unsigned short* dst = rowbase + (size_t)(p + 1) * 512 + c0b + cc;
        uint4 pk;
        pk.x = (unsigned)f2bf(t[cc + 0][p]) | ((unsigned)f2bf(t[cc + 1][p]) << 16);
        pk.y = (unsigned)f2bf(t[cc + 2][p]) | ((unsigned)f2bf(t[cc + 3][p]) << 16);
        pk.z = (unsigned)f2bf(t[cc + 4][p]) | ((unsigned)f2bf(t[cc + 5][p]) << 16);
        pk.w = (unsigned)f2bf(t[cc + 6][p]) | ((unsigned)f2bf(t[cc + 7][p]) << 16);
        *(uint4*)dst = pk;
    }
    if (tid < 64) {
        int ww = (tid >> 5) ? (PAD_IMG - 1) : 0;
        int cp = (tid & 31) * 2;
        *(unsigned int*)(rowbase + (size_t)ww * 512 + c0b + cp) = 0u;
    }
}

// ---- kernel 3: implicit-GEMM conv, 256x128 block, 128x64 waves, BK=64 ----
// Reg-staged, dbuf LDS (A 2x32KB + B 2x16KB), raw lgkm barrier, XOR swz.
// 64 MFMA/wave/step, 72 steps. grid 256 (XCD-swizzled), 1 block/CU.

#define SYNC() do {                                                           \
    asm volatile("s_waitcnt lgkmcnt(0)" ::: "memory");                        \
    __builtin_amdgcn_s_barrier();                                             \
    __builtin_amdgcn_sched_barrier(0);                                        \
} while (0)

// loader: step -> 8 A regs (256x64 slab) + 4 B regs (128x64 slab)
#define LOADSTEP(stp) do {                                                    \
    const int e_  = (stp) >> 3;                                               \
    const int kc_ = ((stp) & 7) << 6;                                         \
    const int kh_ = (e_ * 11) >> 5;                                           \
    const int kw_ = e_ - kh_ * 3;                                             \
    const unsigned short* Ab_ = wt + (size_t)e_ * (COUT * CIN)                \
                                   + (size_t)m0 * 512 + kc_;                  \
    const unsigned short* Bb_ = xpad + bImgBase                               \
                              + (size_t)((h0 + kh_) * PAD_IMG + kw_) * 512    \
                              + kc_;                                          \
    ra0 = *(const uint4*)(Ab_ + aOff0);                                       \
    ra1 = *(const uint4*)(Ab_ + aOff1);                                       \
    ra2 = *(const uint4*)(Ab_ + aOff2);                                       \
    ra3 = *(const uint4*)(Ab_ + aOff3);                                       \
    ra4 = *(const uint4*)(Ab_ + aOff4);                                       \
    ra5 = *(const uint4*)(Ab_ + aOff5);                                       \
    ra6 = *(const uint4*)(Ab_ + aOff6);                                       \
    ra7 = *(const uint4*)(Ab_ + aOff7);                                       \
    rb0 = *(const uint4*)(Bb_ + bOff0);                                       \
    rb1 = *(const uint4*)(Bb_ + bOff1);                                       \
    rb2 = *(const uint4*)(Bb_ + bOff2);                                       \
    rb3 = *(const uint4*)(Bb_ + bOff3);                                       \
} while (0)

#define COMMIT(bufidx) do {                                                   \
    *(uint4*)(&Alds[bufidx][lA0]) = ra0;                                      \
    *(uint4*)(&Alds[bufidx][lA1]) = ra1;                                      \
    *(uint4*)(&Alds[bufidx][lA2]) = ra2;                                      \
    *(uint4*)(&Alds[bufidx][lA3]) = ra3;                                      \
    *(uint4*)(&Alds[bufidx][lA4]) = ra4;                                      \
    *(uint4*)(&Alds[bufidx][lA5]) = ra5;                                      \
    *(uint4*)(&Alds[bufidx][lA6]) = ra6;                                      \
    *(uint4*)(&Alds[bufidx][lA7]) = ra7;                                      \
    *(uint4*)(&Blds[bufidx][lB0]) = rb0;                                      \
    *(uint4*)(&Blds[bufidx][lB1]) = rb1;                                      \
    *(uint4*)(&Blds[bufidx][lB2]) = rb2;                                      \
    *(uint4*)(&Blds[bufidx][lB3]) = rb3;                                      \
} while (0)

__global__ __launch_bounds__(256, 1) void conv_mfma(
    const unsigned short* __restrict__ wt,    // [9][512][512] bf16
    const unsigned short* __restrict__ xpad,  // [16][34][34][512] bf16
    const float* __restrict__ scl,            // [16][512]
    float* __restrict__ out)                  // [16][512][32][32]
{
    __shared__ __align__(16) unsigned short Alds[2][256 * 64];  // 2 x 32 KB
    __shared__ __align__(16) unsigned short Blds[2][128 * 64];  // 2 x 16 KB
    __shared__ float sclds[256];

    const int tid = threadIdx.x;
    // XCD swizzle: 256 blocks, id&7 -> XCD. Per XCD: 16 (h,b)-pairs x 2 m.
    const int id    = blockIdx.x;
    const int xcd   = id & 7;
    const int local = id >> 3;                   // 0..31
    const int gp    = xcd * 16 + (local >> 1);   // 0..127  (h,b) pair
    const int m0  = (local & 1) * 256;
    const int h0  = (gp & 7) * 4;
    const int b   = gp >> 3;

    sclds[tid] = scl[b * 512 + m0 + tid];

    const int wid  = tid >> 6;
    const int lane = tid & 63;
    const int wm = wid & 1, wn = wid >> 1;       // wave 128(M) x 64(N)

    const f32x4 vzero = {0.f, 0.f, 0.f, 0.f};
    f32x4 acc[8][4];
    #pragma unroll
    for (int i = 0; i < 8; ++i)
        #pragma unroll
        for (int j = 0; j < 4; ++j) acc[i][j] = vzero;

    // staging offsets (named scalars -- R9 SROA lesson).
    // A: thread f = r*256+tid owns (row=f>>3 in 0..255, chunk c=f&7).
    // B: r 0..3, rows 0..127. XOR swizzle p = c ^ (row&7).
    int aOff0, aOff1, aOff2, aOff3, aOff4, aOff5, aOff6, aOff7;
    int lA0, lA1, lA2, lA3, lA4, lA5, lA6, lA7;
    int bOff0, bOff1, bOff2, bOff3;
    int lB0, lB1, lB2, lB3;
    {
        int f, row, c, p;
        f = 0 * 256 + tid; row = f >> 3; c = f & 7; p = c ^ (row & 7);
        aOff0 = row * 512 + c * 8;  lA0 = row * 64 + p * 8;
        f = 1 * 256 + tid; row = f >> 3; c = f & 7; p = c ^ (row & 7);
        aOff1 = row * 512 + c * 8;  lA1 = row * 64 + p * 8;
        f = 2 * 256 + tid; row = f >> 3; c = f & 7; p = c ^ (row & 7);
        aOff2 = row * 512 + c * 8;  lA2 = row * 64 + p * 8;
        f = 3 * 256 + tid; row = f >> 3; c = f & 7; p = c ^ (row & 7);
        aOff3 = row * 512 + c * 8;  lA3 = row * 64 + p * 8;
        f = 4 * 256 + tid; row = f >> 3; c = f & 7; p = c ^ (row & 7);
        aOff4 = row * 512 + c * 8;  lA4 = row * 64 + p * 8;
        f = 5 * 256 + tid; row = f >> 3; c = f & 7; p = c ^ (row & 7);
        aOff5 = row * 512 + c * 8;  lA5 = row * 64 + p * 8;
        f = 6 * 256 + tid; row = f >> 3; c = f & 7; p = c ^ (row & 7);
        aOff6 = row * 512 + c * 8;  lA6 = row * 64 + p * 8;
        f = 7 * 256 + tid; row = f >> 3; c = f & 7; p = c ^ (row & 7);
        aOff7 = row * 512 + c * 8;  lA7 = row * 64 + p * 8;

        f = 0 * 256 + tid; row = f >> 3; c = f & 7; p = c ^ (row & 7);
        bOff0 = ((row >> 5) * PAD_IMG + (row & 31)) * 512 + c * 8;
        lB0 = row * 64 + p * 8;
        f = 1 * 256 + tid; row = f >> 3; c = f & 7; p = c ^ (row & 7);
        bOff1 = ((row >> 5) * PAD_IMG + (row & 31)) * 512 + c * 8;
        lB1 = row * 64 + p * 8;
        f = 2 * 256 + tid; row = f >> 3; c = f & 7; p = c ^ (row & 7);
        bOff2 = ((row >> 5) * PAD_IMG + (row & 31)) * 512 + c * 8;
        lB2 = row * 64 + p * 8;
        f = 3 * 256 + tid; row = f >> 3; c = f & 7; p = c ^ (row & 7);
        bOff3 = ((row >> 5) * PAD_IMG + (row & 31)) * 512 + c * 8;
        lB3 = row * 64 + p * 8;
    }

    const size_t bImgBase = (size_t)b * PAD_IMG * PAD_IMG * 512;

    // prefetch state: 12 named uint4 scalars (SROA-safe)
    uint4 ra0, ra1, ra2, ra3, ra4, ra5, ra6, ra7, rb0, rb1, rb2, rb3;

    LOADSTEP(0);

    // fragment read addresses: row R = wavebase+mi*16+rl; chunk (ks*4+kch)
    // at swizzled position ^(R&7); wavebase%16==0 so R&7 = rl&7.
    const int rl   = lane & 15;
    const int kch  = lane >> 4;                  // 0..3
    const int sw   = rl & 7;
    const int swz0 = (kch ^ sw) * 8;             // k 0..31
    const int swz1 = ((kch + 4) ^ sw) * 8;       // k 32..63
    const int arow = (wm * 128 + rl) * 64;
    const int brow = (wn * 64 + rl) * 64;

    for (int step = 0; step < 72; ++step) {
        const int buf = step & 1;
        COMMIT(buf);       // vmcnt waits here are for loads issued last iter
        const int nxt = step + 1 < 72 ? step + 1 : 71;
        LOADSTEP(nxt);     // in flight across the raw barrier
        SYNC();

        // issue ALL frag reads (both k-halves) async, then MFMA: k1 reads
        // overlap MFMA k0 (single wave/SIMD -> intra-wave pipelining).
        bf16x8 a0[8], b0[4], a1[8], b1[4];
        #pragma unroll
        for (int mi = 0; mi < 8; ++mi)
            a0[mi] = *(const bf16x8*)(&Alds[buf][arow + mi * (16 * 64) + swz0]);
        #pragma unroll
        for (int ni = 0; ni < 4; ++ni)
            b0[ni] = *(const bf16x8*)(&Blds[buf][brow + ni * (16 * 64) + swz0]);
        #pragma unroll
        for (int mi = 0; mi < 8; ++mi)
            a1[mi] = *(const bf16x8*)(&Alds[buf][arow + mi * (16 * 64) + swz1]);
        #pragma unroll
        for (int ni = 0; ni < 4; ++ni)
            b1[ni] = *(const bf16x8*)(&Blds[buf][brow + ni * (16 * 64) + swz1]);

        __builtin_amdgcn_s_setprio(1);
        #pragma unroll
        for (int mi = 0; mi < 8; ++mi)
            #pragma unroll
            for (int ni = 0; ni < 4; ++ni)
                acc[mi][ni] = __builtin_amdgcn_mfma_f32_16x16x32_bf16(
                    a0[mi], b0[ni], acc[mi][ni], 0, 0, 0);
        #pragma unroll
        for (int mi = 0; mi < 8; ++mi)
            #pragma unroll
            for (int ni = 0; ni < 4; ++ni)
                acc[mi][ni] = __builtin_amdgcn_mfma_f32_16x16x32_bf16(
                    a1[mi], b1[ni], acc[mi][ni], 0, 0, 0);
        __builtin_amdgcn_s_setprio(0);
        // raw-SYNC safety: each wave drains its own lgkm (reads+writes)
        // before the barrier; step+1 writes target buf^1 whose readers
        // completed before barrier(step). Global loads legitimately cross.
    }

    // epilogue: C[m][n] layout col=lane&15, row=(lane>>4)*4+reg  [m89-verified]
    const int colp = lane & 15;
    const int rowq = (lane >> 4) * 4;
    const int p0 = h0 * 32;
    #pragma unroll
    for (int mi = 0; mi < 8; ++mi) {
        #pragma unroll
        for (int ni = 0; ni < 4; ++ni) {
            const int p = p0 + wn * 64 + ni * 16 + colp;
            #pragma unroll
            for (int r2 = 0; r2 < 4; ++r2) {
                const int ol = wm * 128 + mi * 16 + rowq + r2;
                out[(((size_t)b * 512 + m0 + ol) << 10) + p] =
                    acc[mi][ni][r2] * sclds[ol];
            }
        }
    }
}

extern "C" void kernel_launch(void* const* d_in, const int* in_sizes, int n_in,
                              void* d_out, int out_size, void* d_ws, size_t ws_size,
                              hipStream_t stream) {
    const float* x     = (const float*)d_in[0];  // [16,512,32,32]
    const float* style = (const float*)d_in[1];  // [16,512]
    const float* aw    = (const float*)d_in[2];  // [512,512]
    const float* ab    = (const float*)d_in[3];  // [512]
    const float* cw    = (const float*)d_in[4];  // [512,512,3,3]
    float* out = (float*)d_out;

    char* ws = (char*)d_ws;
    float* s_buf          = (float*)(ws);                      //  32 KB
    float* scl            = (float*)(ws + 32768);              //  32 KB
    float* wsq            = (float*)(ws + 65536);              //   1 MB
    unsigned short* w_t   = (unsigned short*)(ws + 1114112);   // 4.5 MB bf16
    unsigned short* x_pad = (unsigned short*)(ws + 5832704);   // 18.9 MB bf16
    // total ws need: 24,772,608 B

    prep1<<<dim3(3072), 256, 0, stream>>>(cw, style, aw, ab, w_t, wsq, s_buf);
    prep2<<<dim3(6400), 256, 0, stream>>>(x, s_buf, wsq, x_pad, scl);
    conv_mfma<<<dim3(256), 256, 0, stream>>>(w_t, x_pad, scl, out);
}

// Round 9
// 168.487 us; speedup vs baseline: 1.2854x; 1.2854x over previous
//
#include <hip/hip_runtime.h>

// ModulatedConv2d: B=16, IN=512, OUT=512, STYLE=512, K=3, H=W=32
// out[b,o] = scale[b,o] * conv2d(x[b,i]*s[b,i], W[o,i])   (shared weights!)
// Conv = one implicit GEMM: M=512 out-ch, N=16384 (b,px), K=9x512.
// x staged as zero-padded NHWC bf16 -> no boundary masking.
//
// R12: 128x128 block, 4 waves 64x64, BK=64, reg-staged dbuf: 91.6us,
//      MfmaUtil 35%. LDS-pipe-bound: reads 2.42GB + writes 1.21GB.
// R13/R14: B direct-from-global: 160-162us. VMEM-scatter-bound. Dead.
// R15: raw lgkm-only barrier = R12 (91.6) -> vmcnt drain not the cost.
// R16: 256x128, 4 waves 128x64, 1 block/CU: 133us. 1 wave/SIMD killed
//      latency hiding (VALUBusy 28%, MfmaUtil 24%); b128/step only -10%.
// R17 (this): 128x256 block, 8 waves (512 thr) = 2(wm) x 2(wn) x 2(kg):
//      64x128 output tiles, kg splits each BK=64 step's k-halves.
//      0.375 reads/MFMA (12 b128 / 32 MFMA per wave-step), writes
//      6 uint4/thr. Reads 1.81GB + writes 0.91GB -> floor ~52us.
//      Grid 256 = 1 block/CU but 2 waves/SIMD (kg-pairs co-run between
//      barriers = R12's overlap, which R16 lacked). Epilogue: kg=1 -> LDS,
//      kg=0 adds+scales+stores (2 rounds by wm). VGPR ~230 @ (512,2).
//      Predict: conv 60-75us, MfmaUtil 45-58%, WRITE ~33MB (tripwire).

#define BATCH   16
#define CIN     512
#define COUT    512
#define IMG     32
#define PAD_IMG 34

static constexpr float AFF_SCALE = 0.044194173824159216f;  // 1/sqrt(512)
static constexpr float W_SCALE   = 0.014731391274719739f;  // 1/sqrt(512*9)

typedef __bf16 bf16x8 __attribute__((ext_vector_type(8)));
typedef float  f32x4  __attribute__((ext_vector_type(4)));

__device__ inline unsigned short f2bf(float f) {
    union { float f; unsigned int u; } v; v.f = f;
    unsigned int u = v.u;
    unsigned int r = (u + 0x7FFFu + ((u >> 16) & 1u)) >> 16;
    return (unsigned short)r;
}

__device__ inline float waveReduceSum(float v) {
    #pragma unroll
    for (int off = 32; off > 0; off >>= 1) v += __shfl_xor(v, off, 64);
    return v;
}

// ---- kernel 1: fused prep ----
__global__ void prep1(const float* __restrict__ cw,
                      const float* __restrict__ style,
                      const float* __restrict__ aw,
                      const float* __restrict__ ab,
                      unsigned short* __restrict__ w_t,
                      float* __restrict__ wsq,
                      float* __restrict__ s_out) {
    const int tid = threadIdx.x;
    if (blockIdx.x < 1024) {
        __shared__ float wl[2304];
        const float* src = cw + (size_t)blockIdx.x * 2304;
        for (int j = tid; j < 2304; j += 256) wl[j] = src[j];
        __syncthreads();
        const int idx = blockIdx.x * 256 + tid;       // o*512 + i
        const int base = tid * 9;
        float acc = 0.f;
        #pragma unroll
        for (int e = 0; e < 9; ++e) {
            float v = wl[base + e];
            acc += v * v;
            w_t[e * (COUT * CIN) + idx] = f2bf(v);
        }
        wsq[idx] = acc;
    } else {
        const int q = blockIdx.x - 1024;              // 0..2047
        const int b = q >> 7;
        const int i = (q & 127) * 4 + (tid >> 6);
        const int lane = tid & 63;
        float sum = 0.f;
        #pragma unroll
        for (int k = 0; k < 512; k += 64)
            sum += style[b * 512 + k + lane] * aw[i * 512 + k + lane];
        sum = waveReduceSum(sum);
        if (lane == 0)
            s_out[b * 512 + i] = sum * AFF_SCALE + ab[i] + 1.0f;
    }
}

// ---- kernel 2: fused xpad + scale ----
__global__ void prep2(const float* __restrict__ x,
                      const float* __restrict__ s_in,
                      const float* __restrict__ wsq,
                      unsigned short* __restrict__ xpad,
                      float* __restrict__ scl) {
    const int tid = threadIdx.x;
    if (blockIdx.x >= 4352) {
        const int q = blockIdx.x - 4352;              // 0..2047
        const int b = q >> 7;                         // 0..15
        const int o = (q & 127) * 4 + (tid >> 6);     // 0..511
        const int lane = tid & 63;
        float sum = 0.f;
        #pragma unroll
        for (int i = 0; i < 512; i += 64) {
            float sv = s_in[b * 512 + i + lane];
            sum += sv * sv * wsq[o * 512 + i + lane];
        }
        sum = waveReduceSum(sum);
        if (lane == 0)
            scl[b * 512 + o] = W_SCALE * rsqrtf(W_SCALE * W_SCALE * sum + 1e-8f);
        return;
    }
    const int c0   = blockIdx.x & 7;                  // *64 channels
    const int rest = blockIdx.x >> 3;                 // 0..543
    const int hh   = rest % 34;
    const int b    = rest / 34;
    const int c0b  = c0 * 64;
    unsigned short* rowbase = xpad + (((size_t)b * PAD_IMG + hh) * PAD_IMG) * 512;

    if (hh == 0 || hh == PAD_IMG - 1) {
        for (int j = tid; j < 34 * 32; j += 256) {
            int ww = j >> 5, cp = (j & 31) * 2;
            *(unsigned int*)(rowbase + (size_t)ww * 512 + c0b + cp) = 0u;
        }
        return;
    }

    __shared__ float t[64][33];
    const int h = hh - 1;
    {
        const int wx = tid & 31;
        const int cb = (tid >> 5) * 8;
        const float* xb = x + (((size_t)b * 512 + c0b + cb) * IMG + h) * IMG + wx;
        #pragma unroll
        for (int j = 0; j < 8; ++j)
            t[cb + j][wx] = xb[(size_t)j * (IMG * IMG)] * s_in[b * 512 + c0b + cb + j];
    }
    __syncthreads();
    {
        const int p  = tid >> 3;
        const int cc = (tid & 7) * 8;
        unsigned short* dst = rowbase + (size_t)(p + 1) * 512 + c0b + cc;
        uint4 pk;
        pk.x = (unsigned)f2bf(t[cc + 0][p]) | ((unsigned)f2bf(t[cc + 1][p]) << 16);
        pk.y = (unsigned)f2bf(t[cc + 2][p]) | ((unsigned)f2bf(t[cc + 3][p]) << 16);
        pk.z = (unsigned)f2bf(t[cc + 4][p]) | ((unsigned)f2bf(t[cc + 5][p]) << 16);
        pk.w = (unsigned)f2bf(t[cc + 6][p]) | ((unsigned)f2bf(t[cc + 7][p]) << 16);
        *(uint4*)dst = pk;
    }
    if (tid < 64) {
        int ww = (tid >> 5) ? (PAD_IMG - 1) : 0;
        int cp = (tid & 31) * 2;
        *(unsigned int*)(rowbase + (size_t)ww * 512 + c0b + cp) = 0u;
    }
}

// ---- kernel 3: implicit-GEMM conv, 128x256 block, 8 waves, BK=64 ----
// Waves: wm=(wid>>1)&1, wn=wid&1, kg=wid>>2. Output wave tile 64x128;
// kg=0 does k0..31 of each step, kg=1 does k32..63 (partial acc, merged
// in epilogue via LDS). Reg-staged dbuf LDS (A 2x16KB, B 2x32KB), raw
// lgkm barrier, XOR swizzle. grid 256 (XCD-swizzled), 1 block/CU,
// 2 waves/SIMD.

#define SYNC() do {                                                           \
    asm volatile("s_waitcnt lgkmcnt(0)" ::: "memory");                        \
    __builtin_amdgcn_s_barrier();                                             \
    __builtin_amdgcn_sched_barrier(0);                                        \
} while (0)

// loader: step -> 2 A regs (128x64 slab) + 4 B regs (256x64 slab)
#define LOADSTEP(stp) do {                                                    \
    const int e_  = (stp) >> 3;                                               \
    const int kc_ = ((stp) & 7) << 6;                                         \
    const int kh_ = (e_ * 11) >> 5;                                           \
    const int kw_ = e_ - kh_ * 3;                                             \
    const unsigned short* Ab_ = wt + (size_t)e_ * (COUT * CIN)                \
                                   + (size_t)m0 * 512 + kc_;                  \
    const unsigned short* Bb_ = xpad + bImgBase                               \
                              + (size_t)((h0 + kh_) * PAD_IMG + kw_) * 512    \
                              + kc_;                                          \
    ra0 = *(const uint4*)(Ab_ + aOff0);                                       \
    ra1 = *(const uint4*)(Ab_ + aOff1);                                       \
    rb0 = *(const uint4*)(Bb_ + bOff0);                                       \
    rb1 = *(const uint4*)(Bb_ + bOff1);                                       \
    rb2 = *(const uint4*)(Bb_ + bOff2);                                       \
    rb3 = *(const uint4*)(Bb_ + bOff3);                                       \
} while (0)

#define COMMIT(Albuf, Blbuf) do {                                             \
    *(uint4*)((Albuf) + lA0) = ra0;                                           \
    *(uint4*)((Albuf) + lA1) = ra1;                                           \
    *(uint4*)((Blbuf) + lB0) = rb0;                                           \
    *(uint4*)((Blbuf) + lB1) = rb1;                                           \
    *(uint4*)((Blbuf) + lB2) = rb2;                                           \
    *(uint4*)((Blbuf) + lB3) = rb3;                                           \
} while (0)

__global__ __launch_bounds__(512, 2) void conv_mfma(
    const unsigned short* __restrict__ wt,    // [9][512][512] bf16
    const unsigned short* __restrict__ xpad,  // [16][34][34][512] bf16
    const float* __restrict__ scl,            // [16][512]
    float* __restrict__ out)                  // [16][512][32][32]
{
    // 96KB carved: A dbuf 2x16KB, B dbuf 2x32KB; epilogue reuses as f32.
    __shared__ __align__(16) unsigned char smem[98304];
    unsigned short* Alds0 = (unsigned short*)(smem);
    unsigned short* Alds1 = (unsigned short*)(smem + 16384);
    unsigned short* Blds0 = (unsigned short*)(smem + 32768);
    unsigned short* Blds1 = (unsigned short*)(smem + 65536);
    __shared__ float sclds[128];

    const int tid = threadIdx.x;
    // XCD swizzle: 256 blocks, id&7 -> XCD. Per XCD: 8 N-blocks x 4 m.
    const int id    = blockIdx.x;
    const int xcd   = id & 7;
    const int local = id >> 3;                   // 0..31
    const int gp    = xcd * 8 + (local >> 2);    // 0..63  N-block (b, hg)
    const int m0  = (local & 3) * 128;
    const int b   = gp >> 2;                     // 0..15
    const int h0  = (gp & 3) * 8;                // 0,8,16,24

    if (tid < 128) sclds[tid] = scl[b * 512 + m0 + tid];

    const int wid  = tid >> 6;
    const int lane = tid & 63;
    const int wm = (wid >> 1) & 1;               // M half (64 rows)
    const int wn = wid & 1;                      // N half (128 px)
    const int kg = wid >> 2;                     // k-group (k-half of step)

    const f32x4 vzero = {0.f, 0.f, 0.f, 0.f};
    f32x4 acc[4][8];
    #pragma unroll
    for (int i = 0; i < 4; ++i)
        #pragma unroll
        for (int j = 0; j < 8; ++j) acc[i][j] = vzero;

    // staging offsets (named scalars -- R9 SROA lesson). 512 threads:
    // A: f = r*512+tid, r=0..1 -> rows 0..127, chunk c=f&7.
    // B: f = r*512+tid, r=0..3 -> rows 0..255 (px index in N-tile).
    // XOR swizzle p = c ^ (row&7).
    int aOff0, aOff1, lA0, lA1;
    int bOff0, bOff1, bOff2, bOff3, lB0, lB1, lB2, lB3;
    {
        int f, row, c, p;
        f = tid;              row = f >> 3; c = f & 7; p = c ^ (row & 7);
        aOff0 = row * 512 + c * 8;  lA0 = row * 64 + p * 8;
        f = 512 + tid;        row = f >> 3; c = f & 7; p = c ^ (row & 7);
        aOff1 = row * 512 + c * 8;  lA1 = row * 64 + p * 8;

        f = tid;              row = f >> 3; c = f & 7; p = c ^ (row & 7);
        bOff0 = ((row >> 5) * PAD_IMG + (row & 31)) * 512 + c * 8;
        lB0 = row * 64 + p * 8;
        f = 512 + tid;        row = f >> 3; c = f & 7; p = c ^ (row & 7);
        bOff1 = ((row >> 5) * PAD_IMG + (row & 31)) * 512 + c * 8;
        lB1 = row * 64 + p * 8;
        f = 1024 + tid;       row = f >> 3; c = f & 7; p = c ^ (row & 7);
        bOff2 = ((row >> 5) * PAD_IMG + (row & 31)) * 512 + c * 8;
        lB2 = row * 64 + p * 8;
        f = 1536 + tid;       row = f >> 3; c = f & 7; p = c ^ (row & 7);
        bOff3 = ((row >> 5) * PAD_IMG + (row & 31)) * 512 + c * 8;
        lB3 = row * 64 + p * 8;
    }

    const size_t bImgBase = (size_t)b * PAD_IMG * PAD_IMG * 512;

    // prefetch state: 6 named uint4 scalars (SROA-safe)
    uint4 ra0, ra1, rb0, rb1, rb2, rb3;

    LOADSTEP(0);

    // fragment read addresses: this wave reads k-chunk q = kg*4+kch at
    // swizzled position q^(row&7); row&7 = rl&7 (wave bases %16==0).
    const int rl   = lane & 15;
    const int kch  = lane >> 4;                  // 0..3
    const int swz  = ((kg * 4 + kch) ^ (rl & 7)) * 8;
    const int arow = (wm * 64 + rl) * 64;
    const int brow = (wn * 128 + rl) * 64;

    for (int step = 0; step < 72; ++step) {
        unsigned short* Ab_lds = (step & 1) ? Alds1 : Alds0;
        unsigned short* Bb_lds = (step & 1) ? Blds1 : Blds0;
        COMMIT(Ab_lds, Bb_lds);  // vmcnt waits = loads issued last iter
        const int nxt = step + 1 < 72 ? step + 1 : 71;
        LOADSTEP(nxt);           // in flight across the raw barrier
        SYNC();

        bf16x8 af[4], bfr[8];
        #pragma unroll
        for (int mi = 0; mi < 4; ++mi)
            af[mi] = *(const bf16x8*)(Ab_lds + arow + mi * (16 * 64) + swz);
        #pragma unroll
        for (int ni = 0; ni < 8; ++ni)
            bfr[ni] = *(const bf16x8*)(Bb_lds + brow + ni * (16 * 64) + swz);

        __builtin_amdgcn_s_setprio(1);
        #pragma unroll
        for (int mi = 0; mi < 4; ++mi)
            #pragma unroll
            for (int ni = 0; ni < 8; ++ni)
                acc[mi][ni] = __builtin_amdgcn_mfma_f32_16x16x32_bf16(
                    af[mi], bfr[ni], acc[mi][ni], 0, 0, 0);
        __builtin_amdgcn_s_setprio(0);
        // raw-SYNC safety: each wave drains its lgkm (reads+writes) before
        // the barrier; step+1 writes target the other buffer, whose readers
        // completed before barrier(step). Global loads legitimately cross.
    }

    // ---- epilogue: merge kg partials via LDS, scale, store ----
    // C frag layout: col(N)=lane&15, row(M)=(lane>>4)*4+reg [m89-verified]
    const int colp = lane & 15;
    const int rowq = (lane >> 4) * 4;
    float* ep = (float*)smem;                    // 96KB as f32
    float* reg = ep + wn * 8192;                 // 32KB region per wn
    for (int wmr = 0; wmr < 2; ++wmr) {
        __syncthreads();
        if (wm == wmr && kg == 1) {
            #pragma unroll
            for (int mi = 0; mi < 4; ++mi)
                #pragma unroll
                for (int ni = 0; ni < 8; ++ni)
                    *(f32x4*)(reg + ((mi * 8 + ni) * 64 + lane) * 4) =
                        acc[mi][ni];
        }
        __syncthreads();
        if (wm == wmr && kg == 0) {
            #pragma unroll
            for (int mi = 0; mi < 4; ++mi) {
                #pragma unroll
                for (int ni = 0; ni < 8; ++ni) {
                    const f32x4 o =
                        *(const f32x4*)(reg + ((mi * 8 + ni) * 64 + lane) * 4);
                    const int p = h0 * 32 + wn * 128 + ni * 16 + colp;
                    #pragma unroll
                    for (int r2 = 0; r2 < 4; ++r2) {
                        const int ol = wm * 64 + mi * 16 + rowq + r2;
                        out[(((size_t)b * 512 + m0 + ol) << 10) + p] =
                            (acc[mi][ni][r2] + o[r2]) * sclds[ol];
                    }
                }
            }
        }
    }
}

extern "C" void kernel_launch(void* const* d_in, const int* in_sizes, int n_in,
                              void* d_out, int out_size, void* d_ws, size_t ws_size,
                              hipStream_t stream) {
    const float* x     = (const float*)d_in[0];  // [16,512,32,32]
    const float* style = (const float*)d_in[1];  // [16,512]
    const float* aw    = (const float*)d_in[2];  // [512,512]
    const float* ab    = (const float*)d_in[3];  // [512]
    const float* cw    = (const float*)d_in[4];  // [512,512,3,3]
    float* out = (float*)d_out;

    char* ws = (char*)d_ws;
    float* s_buf          = (float*)(ws);                      //  32 KB
    float* scl            = (float*)(ws + 32768);              //  32 KB
    float* wsq            = (float*)(ws + 65536);              //   1 MB
    unsigned short* w_t   = (unsigned short*)(ws + 1114112);   // 4.5 MB bf16
    unsigned short* x_pad = (unsigned short*)(ws + 5832704);   // 18.9 MB bf16
    // total ws need: 24,772,608 B

    prep1<<<dim3(3072), 256, 0, stream>>>(cw, style, aw, ab, w_t, wsq, s_buf);
    prep2<<<dim3(6400), 256, 0, stream>>>(x, s_buf, wsq, x_pad, scl);
    conv_mfma<<<dim3(256), 512, 0, stream>>>(w_t, x_pad, scl, out);
}